// Round 4
// baseline (1822.260 us; speedup 1.0000x reference)
//
#include <hip/hip_runtime.h>
#include <hip/hip_bf16.h>
#include <math.h>

typedef __hip_bfloat16 bf16;

// dtype-flexible input load: flag==1 -> data is float32, else bf16
__device__ __forceinline__ float ldf(const void* p, int i, int f32){
    return f32 ? ((const float*)p)[i] : __bfloat162float(((const bf16*)p)[i]);
}

__device__ __forceinline__ float gelu_tanh(float x){
    float x3 = x*x*x;
    return 0.5f*x*(1.0f + tanhf(0.7978845608028654f*(x + 0.044715f*x3)));
}

// ===================== dtype detection =====================
// bf16 N(0,1) words have exponent <= ~129; f32 data reinterpreted as 16-bit
// words has ~uniform low halves -> exponent>=136 w.p. ~0.47/word.
__global__ void detect_dtype(const void* x, int* flag){
    __shared__ int s;
    if(threadIdx.x==0) s = 0;
    __syncthreads();
    unsigned short u = ((const unsigned short*)x)[threadIdx.x];   // 256 words
    int ex = (u>>7)&0xFF;
    if(ex >= 136) atomicOr(&s, 1);
    __syncthreads();
    if(threadIdx.x==0) flag[0] = s;
}

// ============================ Router ============================
__global__ void r_embed(const void* __restrict__ x, const void* __restrict__ ew,
                        const void* __restrict__ eb, const int* __restrict__ dflag,
                        float* __restrict__ h){
    int f32 = dflag[0];
    int t = blockIdx.x*256 + threadIdx.x;           // 262144
    int d = t & 63, s = (t>>6)&127, b = t>>13;
    h[t] = ldf(x, b*16384 + s, f32) * ldf(ew, d, f32) + ldf(eb, d, f32);
}

__global__ void r_qkv(const float* __restrict__ h, const void* __restrict__ w,
                      const void* __restrict__ bias, const int* __restrict__ dflag,
                      int woff, int boff, float* __restrict__ qkv){
    int f32 = dflag[0];
    int t = blockIdx.x*256 + threadIdx.x;           // 786432
    int j = t % 192; int sb = t/192;
    const float* hr = h + sb*64;
    float acc = ldf(bias, boff + j, f32);
    #pragma unroll
    for(int d=0; d<64; ++d) acc += hr[d]*ldf(w, woff + d*192 + j, f32);
    qkv[t] = acc;
}

__global__ void r_attn(const float* __restrict__ qkv, float* __restrict__ o){
    int t = blockIdx.x*256 + threadIdx.x;           // 16384
    int q = t & 127; int hd = (t>>7)&3; int b = t>>9;
    const float* base = qkv + b*128*192;
    float qv[16];
    #pragma unroll
    for(int d=0; d<16; ++d) qv[d] = base[q*192 + hd*16 + d];
    float sc[128]; float m = -1e30f;
    for(int k=0;k<128;++k){
        const float* kr = base + k*192 + 64 + hd*16;
        float acc=0.f;
        #pragma unroll
        for(int d=0;d<16;++d) acc += qv[d]*kr[d];
        acc *= 0.25f;
        sc[k]=acc; m = fmaxf(m, acc);
    }
    float sum=0.f; float ov[16];
    #pragma unroll
    for(int d=0;d<16;++d) ov[d]=0.f;
    for(int k=0;k<128;++k){
        float p = expf(sc[k]-m); sum += p;
        const float* vr = base + k*192 + 128 + hd*16;
        #pragma unroll
        for(int d=0;d<16;++d) ov[d] += p*vr[d];
    }
    float inv = 1.0f/sum;
    float* orow = o + (b*128+q)*64 + hd*16;
    #pragma unroll
    for(int d=0;d<16;++d) orow[d] = ov[d]*inv;
}

__global__ void r_proj_res(const float* __restrict__ h, const float* __restrict__ o,
                           const void* __restrict__ w, const void* __restrict__ bias,
                           const int* __restrict__ dflag, int woff, int boff,
                           float* __restrict__ r){
    int f32 = dflag[0];
    int t = blockIdx.x*256 + threadIdx.x;           // 262144
    int d = t & 63; int sb = t>>6;
    const float* orow = o + sb*64;
    float acc = ldf(bias, boff + d, f32);
    #pragma unroll
    for(int e=0;e<64;++e) acc += orow[e]*ldf(w, woff + e*64 + d, f32);
    r[t] = h[t] + acc;
}

__global__ void r_ln(const float* __restrict__ r, const void* __restrict__ s,
                     const void* __restrict__ bias, const int* __restrict__ dflag,
                     int off, float* __restrict__ h){
    int f32 = dflag[0];
    int row = blockIdx.x*64 + threadIdx.x;          // 4096 rows
    const float* rr = r + row*64;
    float mu=0.f;
    #pragma unroll
    for(int d=0;d<64;++d) mu += rr[d];
    mu *= (1.0f/64.0f);
    float var=0.f;
    #pragma unroll
    for(int d=0;d<64;++d){ float df = rr[d]-mu; var += df*df; }
    var *= (1.0f/64.0f);
    float inv = rsqrtf(var + 1e-5f);
    float* hr = h + row*64;
    #pragma unroll
    for(int d=0;d<64;++d) hr[d] = (rr[d]-mu)*inv*ldf(s, off+d, f32) + ldf(bias, off+d, f32);
}

// fused FFN: r = h + relu(h@W1+b1)@W2+b2 ; one block per (b,s) row
__global__ void r_ffn(const float* __restrict__ h, const void* __restrict__ w1,
                      const void* __restrict__ b1, const void* __restrict__ w2,
                      const void* __restrict__ b2, const int* __restrict__ dflag,
                      int w1off, int b1off, int w2off, int b2off,
                      float* __restrict__ r){
    __shared__ float hrow[64];
    __shared__ float uval[256];
    int f32 = dflag[0];
    int row = blockIdx.x;                           // 4096
    int tid = threadIdx.x;                          // 256
    if(tid < 64) hrow[tid] = h[row*64 + tid];
    __syncthreads();
    {
        float acc = ldf(b1, b1off + tid, f32);
        #pragma unroll
        for(int d=0; d<64; ++d) acc += hrow[d]*ldf(w1, w1off + d*256 + tid, f32);
        uval[tid] = fmaxf(acc, 0.0f);
    }
    __syncthreads();
    if(tid < 64){
        float acc = ldf(b2, b2off + tid, f32);
        for(int j=0;j<256;++j) acc += uval[j]*ldf(w2, w2off + j*64 + tid, f32);
        r[row*64 + tid] = hrow[tid] + acc;
    }
}

__global__ void r_head(const float* __restrict__ h, const void* __restrict__ fcw,
                       const void* __restrict__ fcb, const int* __restrict__ dflag,
                       int* __restrict__ idx){
    __shared__ float feats[64];
    __shared__ float lg[8];
    int f32 = dflag[0];
    int b = blockIdx.x; int d = threadIdx.x;        // 64 threads
    float acc=0.f;
    for(int s2=0;s2<128;++s2) acc += h[(b*128+s2)*64 + d];
    feats[d] = acc*(1.0f/128.0f);
    __syncthreads();
    if(d<8){
        float a = ldf(fcb, d, f32);
        for(int e=0;e<64;++e) a += feats[e]*ldf(fcw, e*8+d, f32);
        lg[d]=a;
    }
    __syncthreads();
    if(d==0){
        int best=0; float bv=lg[0];
        for(int e=1;e<8;++e) if(lg[e]>bv){bv=lg[e];best=e;}
        idx[b]=best;
    }
}

// ============================ FNO (batch-chunked) ============================
// All kernels operate on a chunk of nb batches starting at global batch b0.
// v chunk layout: [bl][d][h][w], bl in [0,nb)

__global__ void f_lift(const void* __restrict__ x, const void* __restrict__ lw,
                       const void* __restrict__ lb, const int* __restrict__ idx,
                       const int* __restrict__ dflag, int b0, float* __restrict__ v){
    int f32 = dflag[0];
    int t = blockIdx.x*256 + threadIdx.x;           // nb*524288
    int w = t & 127; int h2 = (t>>7)&127; int d = (t>>14)&31; int bl = t>>19;
    int b = b0 + bl;
    int e = idx[b];
    v[t] = ldf(x, b*16384 + h2*128 + w, f32) * ldf(lw, e*32+d, f32) + ldf(lb, e*32+d, f32);
}

// forward DFT along w, ky=0..15.  Xw layout [bi][ky][h] complex, bi = bl*32+i
__global__ void f_dft_w(const float* __restrict__ v, float* __restrict__ Xw){
    __shared__ float cT[128], sT[128];
    int tid = threadIdx.x;
    if(tid<128){ float sv,cv; sincosf(6.283185307179586f*tid/128.0f,&sv,&cv); cT[tid]=cv; sT[tid]=sv; }
    __syncthreads();
    int t = blockIdx.x*256 + tid;                   // nb*65536: (bi*128+h)*16+ky
    int ky = t & 15; int h2 = (t>>4)&127; int bi = t>>11;
    const float* row = v + (bi*128 + h2)*128;
    float re=0.f, im=0.f;
    for(int w=0; w<128; ++w){
        float vv = row[w];
        int a = (ky*w)&127;
        re += vv*cT[a]; im -= vv*sT[a];
    }
    float* out = Xw + ((bi*16 + ky)*128 + h2)*2;
    out[0]=re; out[1]=im;
}

// forward DFT along h at kx in {0..15,112..127}. G layout [bi][kxi][ky] complex
__global__ void f_dft_h(const float* __restrict__ Xw, float* __restrict__ G){
    __shared__ float cT[128], sT[128];
    int tid = threadIdx.x;
    if(tid<128){ float sv,cv; sincosf(6.283185307179586f*tid/128.0f,&sv,&cv); cT[tid]=cv; sT[tid]=sv; }
    __syncthreads();
    int t = blockIdx.x*256 + tid;                   // nb*16384: (bi*32+kxi)*16+ky
    int ky = t & 15; int kxi = (t>>4)&31; int bi = t>>9;
    int kx = kxi<16 ? kxi : kxi+96;
    const float* col = Xw + (bi*16+ky)*128*2;
    float re=0.f, im=0.f;
    for(int h2=0; h2<128; ++h2){
        float cr = col[h2*2], ci = col[h2*2+1];
        int a = (kx*h2)&127;
        float c = cT[a], s2 = sT[a];
        re += cr*c + ci*s2;       // e^{-i a}
        im += ci*c - cr*s2;
    }
    G[t*2]=re; G[t*2+1]=im;
}

__global__ void f_specmul(const float* __restrict__ G, const void* __restrict__ wr,
                          const void* __restrict__ wi, const int* __restrict__ idx,
                          const int* __restrict__ dflag, int l, int b0,
                          float* __restrict__ Go){
    int f32 = dflag[0];
    int t = blockIdx.x*256 + threadIdx.x;           // nb*16384: ((bl*32+o)*32+kxi)*16+ky
    int ky = t & 15; int kxi = (t>>4)&31; int o = (t>>9)&31; int bl = t>>14;
    int e = idx[b0 + bl];
    int side = (kxi>=16) ? 1 : 0; int xm = kxi & 15;
    int wbase = ((((e*4+l)*2+side)*32)*32 + o)*256 + xm*16 + ky;
    const float* gp = G + ((bl*1024 + kxi)*16 + ky)*2;
    float orr=0.f, oii=0.f;
    for(int i=0;i<32;++i){
        float gr = gp[i*1024], gi = gp[i*1024+1];
        float wrv = ldf(wr, wbase + i*8192, f32);
        float wiv = ldf(wi, wbase + i*8192, f32);
        orr += gr*wrv - gi*wiv;
        oii += gr*wiv + gi*wrv;
    }
    Go[t*2]=orr; Go[t*2+1]=oii;
}

// inverse DFT along h: T[bo,h,ky] complex, bo = bl*32+o
__global__ void f_idft_h(const float* __restrict__ Go, float* __restrict__ T){
    __shared__ float cT[128], sT[128];
    int tid = threadIdx.x;
    if(tid<128){ float sv,cv; sincosf(6.283185307179586f*tid/128.0f,&sv,&cv); cT[tid]=cv; sT[tid]=sv; }
    __syncthreads();
    int t = blockIdx.x*256 + tid;                   // nb*65536: (bo*128+h)*16+ky
    int ky = t & 15; int h2 = (t>>4)&127; int bo = t>>11;
    const float* gp = Go + (bo*512 + ky)*2;
    float re=0.f, im=0.f;
    for(int kxi=0;kxi<32;++kxi){
        int kx = kxi<16?kxi:kxi+96;
        float gr = gp[kxi*32], gi = gp[kxi*32+1];
        int a = (kx*h2)&127;
        float c=cT[a], s2=sT[a];
        re += gr*c - gi*s2;       // e^{+i a}
        im += gr*s2 + gi*c;
    }
    float* out = T + t*2;
    out[0]=re; out[1]=im;
}

// inverse rfft along w (16 modes, C2R) + skip matmul + bias + gelu. IN-PLACE on v.
__global__ void f_inv_w_skip(const float* __restrict__ T, float* v,
                             const void* __restrict__ skw, const void* __restrict__ skb,
                             const int* __restrict__ idx, const int* __restrict__ dflag,
                             int l, int act, int b0){
    __shared__ float vrow[32*128];
    __shared__ float Tr[32*16], Ti[32*16];
    __shared__ float sw[32*32];
    __shared__ float sb[32];
    __shared__ float cT[128], sT[128];
    int f32 = dflag[0];
    int bl = blockIdx.x >> 7; int h2 = blockIdx.x & 127;
    int tid = threadIdx.x;                          // 128
    { float sv,cv; sincosf(6.283185307179586f*tid/128.0f,&sv,&cv); cT[tid]=cv; sT[tid]=sv; }
    int e = idx[b0 + bl];
    for(int i=0;i<32;++i) vrow[i*128+tid] = v[((bl*32+i)*128+h2)*128 + tid];
    for(int k=tid; k<512; k+=128){
        int o=k>>4, ky=k&15;
        const float* tp = T + (((bl*32+o)*128+h2)*16+ky)*2;
        Tr[k]=tp[0]; Ti[k]=tp[1];
    }
    for(int k=tid;k<1024;k+=128) sw[k] = ldf(skw, (e*4+l)*1024 + k, f32);   // [i][o]
    if(tid<32) sb[tid] = ldf(skb, (e*4+l)*32 + tid, f32);
    __syncthreads();
    int w = tid;
    float vv[32];
    #pragma unroll
    for(int i=0;i<32;++i) vv[i]=vrow[i*128+w];
    for(int o=0;o<32;++o){
        float spec = Tr[o*16];                      // imag of DC ignored (C2R)
        #pragma unroll
        for(int ky=1;ky<16;++ky){
            int a = (ky*w)&127;
            spec += 2.0f*(Tr[o*16+ky]*cT[a] - Ti[o*16+ky]*sT[a]);
        }
        spec *= (1.0f/16384.0f);                    // 1/(H*W)
        float acc = sb[o];
        #pragma unroll
        for(int i=0;i<32;++i) acc += vv[i]*sw[i*32+o];
        float val = spec + acc;
        if(act) val = gelu_tanh(val);
        v[((bl*32+o)*128+h2)*128 + w] = val;
    }
}

// final projection — OUTPUT IS FLOAT32 (reference output dtype)
__global__ void f_proj(const float* __restrict__ vin, const void* __restrict__ p1w,
                       const void* __restrict__ p1b, const void* __restrict__ p2w,
                       const void* __restrict__ p2b, const int* __restrict__ idx,
                       const int* __restrict__ dflag, int b0, float* __restrict__ out){
    __shared__ float vrow[32*128];
    __shared__ float w1[32*128];
    __shared__ float b1[128];
    __shared__ float w2[128];
    int f32 = dflag[0];
    int bl = blockIdx.x >> 7; int h2 = blockIdx.x & 127;
    int b = b0 + bl;
    int tid = threadIdx.x;                          // 128
    int e = idx[b];
    for(int i=0;i<32;++i) vrow[i*128+tid] = vin[((bl*32+i)*128+h2)*128 + tid];
    for(int i=0;i<32;++i) w1[i*128+tid] = ldf(p1w, (e*32+i)*128 + tid, f32);
    b1[tid] = ldf(p1b, e*128+tid, f32);
    w2[tid] = ldf(p2w, e*128+tid, f32);
    __syncthreads();
    int w = tid;
    float vv[32];
    #pragma unroll
    for(int i=0;i<32;++i) vv[i]=vrow[i*128+w];
    float acc = ldf(p2b, e, f32);
    for(int o=0;o<128;++o){
        float t2 = b1[o];
        #pragma unroll
        for(int i=0;i<32;++i) t2 += vv[i]*w1[i*128+o];
        acc += w2[o]*gelu_tanh(t2);
    }
    out[b*16384 + h2*128 + w] = acc;
}

// ============================ launch ============================
extern "C" void kernel_launch(void* const* d_in, const int* in_sizes, int n_in,
                              void* d_out, int out_size, void* d_ws, size_t ws_size,
                              hipStream_t stream){
    const void* x      = d_in[0];
    const void* enc_w  = d_in[1];
    const void* enc_b  = d_in[2];
    const void* qkv_w  = d_in[3];
    const void* qkv_b  = d_in[4];
    const void* ao_w   = d_in[5];
    const void* ao_b   = d_in[6];
    const void* ln1_s  = d_in[7];
    const void* ln1_b  = d_in[8];
    const void* ff1_w  = d_in[9];
    const void* ff1_b  = d_in[10];
    const void* ff2_w  = d_in[11];
    const void* ff2_b  = d_in[12];
    const void* ln2_s  = d_in[13];
    const void* ln2_b  = d_in[14];
    const void* fc_w   = d_in[15];
    const void* fc_b   = d_in[16];
    const void* lift_w = d_in[17];
    const void* lift_b = d_in[18];
    const void* spec_wr= d_in[19];
    const void* spec_wi= d_in[20];
    const void* skip_w = d_in[21];
    const void* skip_b = d_in[22];
    const void* p1_w   = d_in[23];
    const void* p1_b   = d_in[24];
    const void* p2_w   = d_in[25];
    const void* p2_b   = d_in[26];

    // ---- adaptive workspace sizing ----
    // header: 64 floats (dflag + idx). FNO chunk of nb batches needs
    // nb*851968 floats (v 524288 + Xw 131072 + G 32768 + Go 32768 + T 131072).
    // Router scratch: 1,572,864 floats, aliases the FNO region (runs first).
    int*   dflag = (int*)d_ws;
    int*   idx   = dflag + 8;
    float* base  = (float*)d_ws + 64;

    size_t avail_fl = (ws_size/4 > 64) ? (ws_size/4 - 64) : 0;
    int nb = 1;
    for(int c = 32; c >= 1; c >>= 1){
        if((size_t)c*851968 <= avail_fl){ nb = c; break; }
    }

    // router scratch (aliased)
    float* hbuf  = base;                         // 262144
    float* qkvb  = hbuf + 262144;                // 786432
    float* obuf  = qkvb + 786432;                // 262144
    float* rbuf  = obuf + 262144;                // 262144  (total 1,572,864)

    detect_dtype<<<1,256,0,stream>>>(x, dflag);

    // ---- router ----
    r_embed<<<1024,256,0,stream>>>(x, enc_w, enc_b, dflag, hbuf);
    for(int l=0;l<2;++l){
        r_qkv<<<3072,256,0,stream>>>(hbuf, qkv_w, qkv_b, dflag, l*64*192, l*192, qkvb);
        r_attn<<<64,256,0,stream>>>(qkvb, obuf);
        r_proj_res<<<1024,256,0,stream>>>(hbuf, obuf, ao_w, ao_b, dflag, l*64*64, l*64, rbuf);
        r_ln<<<64,64,0,stream>>>(rbuf, ln1_s, ln1_b, dflag, l*64, hbuf);
        r_ffn<<<4096,256,0,stream>>>(hbuf, ff1_w, ff1_b, ff2_w, ff2_b, dflag,
                                     l*64*256, l*256, l*256*64, l*64, rbuf);
        r_ln<<<64,64,0,stream>>>(rbuf, ln2_s, ln2_b, dflag, l*64, hbuf);
    }
    r_head<<<32,64,0,stream>>>(hbuf, fc_w, fc_b, dflag, idx);

    // ---- FNO, batch-chunked ----
    for(int b0 = 0; b0 < 32; b0 += nb){
        float* vC = base;                        // nb*524288
        float* Xw = vC + (size_t)nb*524288;      // nb*131072
        float* G  = Xw + (size_t)nb*131072;      // nb*32768
        float* Go = G  + (size_t)nb*32768;       // nb*32768
        float* T  = Go + (size_t)nb*32768;       // nb*131072

        f_lift<<<nb*2048,256,0,stream>>>(x, lift_w, lift_b, idx, dflag, b0, vC);
        for(int l=0;l<4;++l){
            f_dft_w  <<<nb*256,256,0,stream>>>(vC, Xw);
            f_dft_h  <<<nb*64, 256,0,stream>>>(Xw, G);
            f_specmul<<<nb*64, 256,0,stream>>>(G, spec_wr, spec_wi, idx, dflag, l, b0, Go);
            f_idft_h <<<nb*256,256,0,stream>>>(Go, T);
            f_inv_w_skip<<<nb*128,128,0,stream>>>(T, vC, skip_w, skip_b, idx, dflag,
                                                  l, (l<3)?1:0, b0);
        }
        f_proj<<<nb*128,128,0,stream>>>(vC, p1_w, p1_b, p2_w, p2_b, idx, dflag, b0,
                                        (float*)d_out);
    }
}

// Round 5
// 1451.573 us; speedup vs baseline: 1.2554x; 1.2554x over previous
//
#include <hip/hip_runtime.h>
#include <hip/hip_bf16.h>
#include <math.h>

__device__ __forceinline__ float gelu_f(float x){
    float u = 0.7978845608028654f*(x + 0.044715f*x*x*x);
    float e = __expf(2.0f*u);
    float th = 1.0f - 2.0f/(e + 1.0f);
    return 0.5f*x*(1.0f + th);
}

// ============================ Router ============================
__global__ void r_embed(const float* __restrict__ x, const float* __restrict__ ew,
                        const float* __restrict__ eb, float* __restrict__ h){
    int t = blockIdx.x*256 + threadIdx.x;           // 262144
    int d = t & 63, s = (t>>6)&127, b = t>>13;
    h[t] = x[b*16384 + s]*ew[d] + eb[d];
}

__global__ void r_qkv(const float* __restrict__ h, const float* __restrict__ w,
                      const float* __restrict__ bias, int woff, int boff,
                      float* __restrict__ qkv){
    int t = blockIdx.x*256 + threadIdx.x;           // 786432
    int j = t % 192; int sb = t/192;
    const float* hr = h + sb*64;
    float acc = bias[boff + j];
    #pragma unroll
    for(int d=0; d<64; ++d) acc += hr[d]*w[woff + d*192 + j];
    qkv[t] = acc;
}

__global__ void r_attn(const float* __restrict__ qkv, float* __restrict__ o){
    int t = blockIdx.x*256 + threadIdx.x;           // 16384
    int q = t & 127; int hd = (t>>7)&3; int b = t>>9;
    const float* base = qkv + b*128*192;
    float qv[16];
    #pragma unroll
    for(int d=0; d<16; ++d) qv[d] = base[q*192 + hd*16 + d];
    float sc[128]; float m = -1e30f;
    for(int k=0;k<128;++k){
        const float* kr = base + k*192 + 64 + hd*16;
        float acc=0.f;
        #pragma unroll
        for(int d=0;d<16;++d) acc += qv[d]*kr[d];
        acc *= 0.25f;
        sc[k]=acc; m = fmaxf(m, acc);
    }
    float sum=0.f; float ov[16];
    #pragma unroll
    for(int d=0;d<16;++d) ov[d]=0.f;
    for(int k=0;k<128;++k){
        float p = __expf(sc[k]-m); sum += p;
        const float* vr = base + k*192 + 128 + hd*16;
        #pragma unroll
        for(int d=0;d<16;++d) ov[d] += p*vr[d];
    }
    float inv = 1.0f/sum;
    float* orow = o + (b*128+q)*64 + hd*16;
    #pragma unroll
    for(int d=0;d<16;++d) orow[d] = ov[d]*inv;
}

__global__ void r_proj_res(const float* __restrict__ h, const float* __restrict__ o,
                           const float* __restrict__ w, const float* __restrict__ bias,
                           int woff, int boff, float* __restrict__ r){
    int t = blockIdx.x*256 + threadIdx.x;           // 262144
    int d = t & 63; int sb = t>>6;
    const float* orow = o + sb*64;
    float acc = bias[boff + d];
    #pragma unroll
    for(int e=0;e<64;++e) acc += orow[e]*w[woff + e*64 + d];
    r[t] = h[t] + acc;
}

__global__ void r_ln(const float* __restrict__ r, const float* __restrict__ s,
                     const float* __restrict__ bias, int off, float* __restrict__ h){
    int row = blockIdx.x*64 + threadIdx.x;          // 4096 rows
    const float* rr = r + row*64;
    float mu=0.f;
    #pragma unroll
    for(int d=0;d<64;++d) mu += rr[d];
    mu *= (1.0f/64.0f);
    float var=0.f;
    #pragma unroll
    for(int d=0;d<64;++d){ float df = rr[d]-mu; var += df*df; }
    var *= (1.0f/64.0f);
    float inv = rsqrtf(var + 1e-5f);
    float* hr = h + row*64;
    #pragma unroll
    for(int d=0;d<64;++d) hr[d] = (rr[d]-mu)*inv*s[off+d] + bias[off+d];
}

__global__ void r_ffn(const float* __restrict__ h, const float* __restrict__ w1,
                      const float* __restrict__ b1, const float* __restrict__ w2,
                      const float* __restrict__ b2,
                      int w1off, int b1off, int w2off, int b2off,
                      float* __restrict__ r){
    __shared__ float hrow[64];
    __shared__ float uval[256];
    int row = blockIdx.x;                           // 4096
    int tid = threadIdx.x;                          // 256
    if(tid < 64) hrow[tid] = h[row*64 + tid];
    __syncthreads();
    {
        float acc = b1[b1off + tid];
        #pragma unroll
        for(int d=0; d<64; ++d) acc += hrow[d]*w1[w1off + d*256 + tid];
        uval[tid] = fmaxf(acc, 0.0f);
    }
    __syncthreads();
    if(tid < 64){
        float acc = b2[b2off + tid];
        for(int j=0;j<256;++j) acc += uval[j]*w2[w2off + j*64 + tid];
        r[row*64 + tid] = hrow[tid] + acc;
    }
}

__global__ void r_head(const float* __restrict__ h, const float* __restrict__ fcw,
                       const float* __restrict__ fcb, int* __restrict__ idx){
    __shared__ float feats[64];
    __shared__ float lg[8];
    int b = blockIdx.x; int d = threadIdx.x;        // 64 threads
    float acc=0.f;
    for(int s2=0;s2<128;++s2) acc += h[(b*128+s2)*64 + d];
    feats[d] = acc*(1.0f/128.0f);
    __syncthreads();
    if(d<8){
        float a = fcb[d];
        for(int e=0;e<64;++e) a += feats[e]*fcw[e*8+d];
        lg[d]=a;
    }
    __syncthreads();
    if(d==0){
        int best=0; float bv=lg[0];
        for(int e=1;e<8;++e) if(lg[e]>bv){bv=lg[e];best=e;}
        idx[b]=best;
    }
}

// ============================ FNO (batch-chunked) ============================
__global__ void f_lift(const float* __restrict__ x, const float* __restrict__ lw,
                       const float* __restrict__ lb, const int* __restrict__ idx,
                       int b0, float* __restrict__ v){
    int t = blockIdx.x*256 + threadIdx.x;           // nb*524288
    int w = t & 127; int h2 = (t>>7)&127; int d = (t>>14)&31; int bl = t>>19;
    int b = b0 + bl;
    int e = idx[b];
    v[t] = x[b*16384 + h2*128 + w]*lw[e*32+d] + lb[e*32+d];
}

// forward DFT along w, ky=0..15.  Radix-4 over w + phasor recurrence over ky.
// Thread = (bi, h); v row streamed from global as float4.  Xw[bi][ky][h] cplx.
__global__ __launch_bounds__(256) void f_dft_w(const float* __restrict__ v,
                                               float* __restrict__ Xw){
    __shared__ float cT[128], sT[128];
    int tid = threadIdx.x;                          // 256
    if(tid<128){ float sv,cv; __sincosf(6.283185307179586f*tid/128.0f,&sv,&cv); cT[tid]=cv; sT[tid]=sv; }
    __syncthreads();
    int bi = blockIdx.x*2 + (tid>>7);
    int h  = tid & 127;
    const float* row = v + (bi*128 + h)*128;
    float Xr[16], Xi[16];
    #pragma unroll
    for(int k=0;k<16;++k){ Xr[k]=0.f; Xi[k]=0.f; }
    #pragma unroll
    for(int j=0;j<8;++j){
        float4 a = *(const float4*)(row + 4*j);
        float4 b = *(const float4*)(row + 4*j + 32);
        float4 c = *(const float4*)(row + 4*j + 64);
        float4 d = *(const float4*)(row + 4*j + 96);
        #pragma unroll
        for(int r=0;r<4;++r){
            int g = 4*j + r;
            float va = (r==0)?a.x:(r==1)?a.y:(r==2)?a.z:a.w;
            float vb = (r==0)?b.x:(r==1)?b.y:(r==2)?b.z:b.w;
            float vc = (r==0)?c.x:(r==1)?c.y:(r==2)?c.z:c.w;
            float vd = (r==0)?d.x:(r==1)?d.y:(r==2)?d.z:d.w;
            float s1=va+vc, s2=vb+vd, d1=va-vc, d2=vb-vd;
            float rsum=s1+s2, rdif=s1-s2;
            float pc=cT[g], ps=-sT[g];              // p = e^{-i g θ}
            float cr=1.f, ci=0.f;
            #pragma unroll
            for(int ky=0;ky<16;++ky){
                int m = ky&3;
                if(m==0){ Xr[ky]+=cr*rsum; Xi[ky]+=ci*rsum; }
                else if(m==1){ Xr[ky]+=cr*d1+ci*d2; Xi[ky]+=ci*d1-cr*d2; }
                else if(m==2){ Xr[ky]+=cr*rdif; Xi[ky]+=ci*rdif; }
                else { Xr[ky]+=cr*d1-ci*d2; Xi[ky]+=ci*d1+cr*d2; }
                float tt=cr*pc-ci*ps; ci=cr*ps+ci*pc; cr=tt;
            }
        }
    }
    #pragma unroll
    for(int ky=0;ky<16;++ky){
        float2* out = (float2*)(Xw + ((bi*16+ky)*128 + h)*2);
        *out = make_float2(Xr[ky], Xi[ky]);
    }
}

// forward DFT along h at kx in {0..15,112..127}. Block per bi, thread=(ky,kg).
// G layout [bi][kxi][ky] complex
__global__ __launch_bounds__(128) void f_dft_h(const float* __restrict__ Xw,
                                               float* __restrict__ G){
    __shared__ float cT[128], sT[128];
    __shared__ float X[16*130*2];                   // [ky][h] cplx, stride 130
    int tid = threadIdx.x;                          // 128
    { float sv,cv; __sincosf(6.283185307179586f*tid/128.0f,&sv,&cv); cT[tid]=cv; sT[tid]=sv; }
    int bi = blockIdx.x;
    const float2* src = (const float2*)(Xw + bi*4096);
    for(int k=tid;k<2048;k+=128){
        int ky=k>>7, h=k&127;
        float2 t2 = src[k];
        X[(ky*130+h)*2]=t2.x; X[(ky*130+h)*2+1]=t2.y;
    }
    __syncthreads();
    int ky = tid&15, kg = tid>>4;
    int kx0 = kg, kx1 = kg+8, kx2 = kg+112, kx3 = kg+120;
    float qc[4], qs[4];
    qc[0]=cT[kx0]; qs[0]=-sT[kx0];
    qc[1]=cT[kx1]; qs[1]=-sT[kx1];
    qc[2]=cT[kx2&127]; qs[2]=-sT[kx2&127];
    qc[3]=cT[kx3&127]; qs[3]=-sT[kx3&127];
    float cr[4]={1.f,1.f,1.f,1.f}, ci[4]={0.f,0.f,0.f,0.f};
    float Gr[4]={0.f,0.f,0.f,0.f}, Gi[4]={0.f,0.f,0.f,0.f};
    for(int h=0;h<128;++h){
        float Xr=X[(ky*130+h)*2], Xi2=X[(ky*130+h)*2+1];
        #pragma unroll
        for(int m=0;m<4;++m){
            Gr[m] += Xr*cr[m] - Xi2*ci[m];
            Gi[m] += Xr*ci[m] + Xi2*cr[m];
            float t=cr[m]*qc[m]-ci[m]*qs[m]; ci[m]=cr[m]*qs[m]+ci[m]*qc[m]; cr[m]=t;
        }
    }
    #pragma unroll
    for(int m=0;m<4;++m){
        int kxi = kg + 8*m;
        G[((bi*32+kxi)*16+ky)*2]   = Gr[m];
        G[((bi*32+kxi)*16+ky)*2+1] = Gi[m];
    }
}

__global__ void f_specmul(const float* __restrict__ G, const float* __restrict__ wr,
                          const float* __restrict__ wi, const int* __restrict__ idx,
                          int l, int b0, float* __restrict__ Go){
    int t = blockIdx.x*256 + threadIdx.x;           // nb*16384
    int ky = t & 15; int kxi = (t>>4)&31; int o = (t>>9)&31; int bl = t>>14;
    int e = __builtin_amdgcn_readfirstlane(idx[b0 + bl]);
    int side = (kxi>=16) ? 1 : 0; int xm = kxi & 15;
    int wbase = ((((e*4+l)*2+side)*32)*32 + o)*256 + xm*16 + ky;
    const float* gp = G + ((bl*1024 + kxi)*16 + ky)*2;
    float orr=0.f, oii=0.f;
    #pragma unroll 8
    for(int i=0;i<32;++i){
        float gr = gp[i*1024], gi = gp[i*1024+1];
        float wrv = wr[wbase + i*8192];
        float wiv = wi[wbase + i*8192];
        orr += gr*wrv - gi*wiv;
        oii += gr*wiv + gi*wrv;
    }
    Go[t*2]=orr; Go[t*2+1]=oii;
}

// inverse DFT along h. Block per bo=(bl,o), thread=h. Go block-uniform -> s_load.
// T layout [bo][h][ky] complex (contiguous 32 floats per (bo,h)).
__global__ __launch_bounds__(128) void f_idft_h(const float* __restrict__ Go,
                                                float* __restrict__ T){
    __shared__ float cT[128], sT[128];
    int tid = threadIdx.x;                          // 128
    { float sv,cv; __sincosf(6.283185307179586f*tid/128.0f,&sv,&cv); cT[tid]=cv; sT[tid]=sv; }
    __syncthreads();
    int bo = blockIdx.x;
    const float* g = Go + bo*1024;                  // [kxi][ky] cplx
    int h = tid;
    float Mc = cT[h], Ms = sT[h];                   // e^{+i h θ}
    float Tr[16], Ti[16];
    #pragma unroll
    for(int k=0;k<16;++k){ Tr[k]=0.f; Ti[k]=0.f; }
    {   // kxi = 0..15, cur = e^{+i kxi h θ}
        float cr=1.f, ci=0.f;
        for(int kxi=0;kxi<16;++kxi){
            #pragma unroll
            for(int ky=0;ky<16;++ky){
                float gr=g[(kxi*16+ky)*2], gi=g[(kxi*16+ky)*2+1];
                Tr[ky] += gr*cr - gi*ci;
                Ti[ky] += gr*ci + gi*cr;
            }
            float t=cr*Mc-ci*Ms; ci=cr*Ms+ci*Mc; cr=t;
        }
    }
    {   // kxi = 31..16  <->  e^{-i m h θ}, m=1..16
        float cr=1.f, ci=0.f;
        for(int m=1;m<=16;++m){
            float t=cr*Mc+ci*Ms; ci=ci*Mc-cr*Ms; cr=t;   // cur *= conj(M)
            int kxi = 32 - m;
            #pragma unroll
            for(int ky=0;ky<16;++ky){
                float gr=g[(kxi*16+ky)*2], gi=g[(kxi*16+ky)*2+1];
                Tr[ky] += gr*cr - gi*ci;
                Ti[ky] += gr*ci + gi*cr;
            }
        }
    }
    float* out = T + (bo*128 + h)*32;
    #pragma unroll
    for(int k=0;k<8;++k){
        *(float4*)(out + 4*k) = make_float4(Tr[2*k], Ti[2*k], Tr[2*k+1], Ti[2*k+1]);
    }
}

// C2R inverse along w (16 modes) + skip matmul + bias + gelu. IN-PLACE on v.
// Block (bl,h2), thread=w. Weights/T block-uniform -> SGPR loads.
__global__ __launch_bounds__(128) void f_inv_w_skip(const float* __restrict__ T,
                             float* __restrict__ v,
                             const float* __restrict__ skw, const float* __restrict__ skb,
                             const int* __restrict__ idx, int l, int act, int b0){
    __shared__ float cT[128], sT[128];
    int tid = threadIdx.x;                          // 128
    { float sv,cv; __sincosf(6.283185307179586f*tid/128.0f,&sv,&cv); cT[tid]=cv; sT[tid]=sv; }
    __syncthreads();
    int bl = blockIdx.x >> 7; int h2 = blockIdx.x & 127;
    int e = __builtin_amdgcn_readfirstlane(idx[b0 + bl]);
    int w = tid;
    // per-lane pixel values
    float vv[32];
    #pragma unroll
    for(int i=0;i<32;++i) vv[i] = v[((bl*32+i)*128+h2)*128 + w];
    // skip: acc[o] = skb[o] + sum_i vv[i]*skw[i][o]
    const float* swp = skw + (e*4+l)*1024;
    const float* sbp = skb + (e*4+l)*32;
    float acc[32];
    #pragma unroll
    for(int o=0;o<32;++o) acc[o] = sbp[o];
    for(int i=0;i<32;++i){
        float vi = vv[i];
        const float* wrow = swp + i*32;
        #pragma unroll
        for(int o=0;o<32;++o) acc[o] += vi*wrow[o];
    }
    // per-lane C2R twiddles: C[ky]=2cos(ky w θ), S[ky]=2sin(ky w θ)
    float C[16], S[16];
    {
        float bc=cT[w], bs=sT[w];
        float cr=bc, ci=bs;
        C[0]=1.f; S[0]=0.f;
        #pragma unroll
        for(int ky=1;ky<16;++ky){
            C[ky]=2.f*cr; S[ky]=2.f*ci;
            float t=cr*bc-ci*bs; ci=cr*bs+ci*bc; cr=t;
        }
    }
    // spectral + combine + store
    for(int o=0;o<32;++o){
        const float* Tb = T + ((bl*32+o)*128 + h2)*32;   // 16 cplx contiguous
        float spec = Tb[0];
        #pragma unroll
        for(int ky=1;ky<16;++ky) spec += Tb[2*ky]*C[ky] - Tb[2*ky+1]*S[ky];
        float val = spec*(1.0f/16384.0f) + acc[o];
        if(act) val = gelu_f(val);
        v[((bl*32+o)*128+h2)*128 + w] = val;
    }
}

// final projection: out = p2b + sum_o p2[o]*gelu(p1b[o] + sum_i v[i]*p1[i][o])
__global__ __launch_bounds__(128) void f_proj(const float* __restrict__ vin,
                       const float* __restrict__ p1w, const float* __restrict__ p1b,
                       const float* __restrict__ p2w, const float* __restrict__ p2b,
                       const int* __restrict__ idx, int b0, float* __restrict__ out){
    int bl = blockIdx.x >> 7; int h2 = blockIdx.x & 127;
    int b = b0 + bl;
    int tid = threadIdx.x;                          // 128
    int e = __builtin_amdgcn_readfirstlane(idx[b]);
    int w = tid;
    float vv[32];
    #pragma unroll
    for(int i=0;i<32;++i) vv[i] = vin[((bl*32+i)*128+h2)*128 + w];
    const float* w1 = p1w + e*4096;                 // [i][o] 32x128
    const float* b1 = p1b + e*128;
    const float* w2 = p2w + e*128;
    float res = p2b[e];
    for(int og=0; og<16; ++og){
        int o0 = og*8;
        float a[8];
        #pragma unroll
        for(int j=0;j<8;++j) a[j] = b1[o0+j];
        for(int i=0;i<32;++i){
            float vi = vv[i];
            const float* wr = w1 + i*128 + o0;
            #pragma unroll
            for(int j=0;j<8;++j) a[j] += vi*wr[j];
        }
        #pragma unroll
        for(int j=0;j<8;++j) res += w2[o0+j]*gelu_f(a[j]);
    }
    out[b*16384 + h2*128 + w] = res;
}

// ============================ launch ============================
extern "C" void kernel_launch(void* const* d_in, const int* in_sizes, int n_in,
                              void* d_out, int out_size, void* d_ws, size_t ws_size,
                              hipStream_t stream){
    const float* x      = (const float*)d_in[0];
    const float* enc_w  = (const float*)d_in[1];
    const float* enc_b  = (const float*)d_in[2];
    const float* qkv_w  = (const float*)d_in[3];
    const float* qkv_b  = (const float*)d_in[4];
    const float* ao_w   = (const float*)d_in[5];
    const float* ao_b   = (const float*)d_in[6];
    const float* ln1_s  = (const float*)d_in[7];
    const float* ln1_b  = (const float*)d_in[8];
    const float* ff1_w  = (const float*)d_in[9];
    const float* ff1_b  = (const float*)d_in[10];
    const float* ff2_w  = (const float*)d_in[11];
    const float* ff2_b  = (const float*)d_in[12];
    const float* ln2_s  = (const float*)d_in[13];
    const float* ln2_b  = (const float*)d_in[14];
    const float* fc_w   = (const float*)d_in[15];
    const float* fc_b   = (const float*)d_in[16];
    const float* lift_w = (const float*)d_in[17];
    const float* lift_b = (const float*)d_in[18];
    const float* spec_wr= (const float*)d_in[19];
    const float* spec_wi= (const float*)d_in[20];
    const float* skip_w = (const float*)d_in[21];
    const float* skip_b = (const float*)d_in[22];
    const float* p1_w   = (const float*)d_in[23];
    const float* p1_b   = (const float*)d_in[24];
    const float* p2_w   = (const float*)d_in[25];
    const float* p2_b   = (const float*)d_in[26];

    // workspace: header 64 floats; FNO chunk of nb batches = nb*851968 floats
    // (v 524288 + Xw 131072 + G 32768 + Go 32768 + T 131072). Router scratch
    // (1,572,864 fl) aliases the FNO region (router completes first).
    int*   idx   = (int*)d_ws + 8;
    float* base  = (float*)d_ws + 64;

    size_t avail_fl = (ws_size/4 > 64) ? (ws_size/4 - 64) : 0;
    int nb = 1;
    for(int c = 32; c >= 1; c >>= 1){
        if((size_t)c*851968 <= avail_fl){ nb = c; break; }
    }

    float* hbuf  = base;                         // 262144
    float* qkvb  = hbuf + 262144;                // 786432
    float* obuf  = qkvb + 786432;                // 262144
    float* rbuf  = obuf + 262144;                // 262144

    // ---- router ----
    r_embed<<<1024,256,0,stream>>>(x, enc_w, enc_b, hbuf);
    for(int l=0;l<2;++l){
        r_qkv<<<3072,256,0,stream>>>(hbuf, qkv_w, qkv_b, l*64*192, l*192, qkvb);
        r_attn<<<64,256,0,stream>>>(qkvb, obuf);
        r_proj_res<<<1024,256,0,stream>>>(hbuf, obuf, ao_w, ao_b, l*64*64, l*64, rbuf);
        r_ln<<<64,64,0,stream>>>(rbuf, ln1_s, ln1_b, l*64, hbuf);
        r_ffn<<<4096,256,0,stream>>>(hbuf, ff1_w, ff1_b, ff2_w, ff2_b,
                                     l*64*256, l*256, l*256*64, l*64, rbuf);
        r_ln<<<64,64,0,stream>>>(rbuf, ln2_s, ln2_b, l*64, hbuf);
    }
    r_head<<<32,64,0,stream>>>(hbuf, fc_w, fc_b, idx);

    // ---- FNO, batch-chunked ----
    for(int b0 = 0; b0 < 32; b0 += nb){
        float* vC = base;                        // nb*524288
        float* Xw = vC + (size_t)nb*524288;      // nb*131072
        float* G  = Xw + (size_t)nb*131072;      // nb*32768
        float* Go = G  + (size_t)nb*32768;       // nb*32768
        float* T  = Go + (size_t)nb*32768;       // nb*131072

        f_lift<<<nb*2048,256,0,stream>>>(x, lift_w, lift_b, idx, b0, vC);
        for(int l=0;l<4;++l){
            f_dft_w  <<<nb*16, 256,0,stream>>>(vC, Xw);
            f_dft_h  <<<nb*32, 128,0,stream>>>(Xw, G);
            f_specmul<<<nb*64, 256,0,stream>>>(G, spec_wr, spec_wi, idx, l, b0, Go);
            f_idft_h <<<nb*32, 128,0,stream>>>(Go, T);
            f_inv_w_skip<<<nb*128,128,0,stream>>>(T, vC, skip_w, skip_b, idx,
                                                  l, (l<3)?1:0, b0);
        }
        f_proj<<<nb*128,128,0,stream>>>(vC, p1_w, p1_b, p2_w, p2_b, idx, b0,
                                        (float*)d_out);
    }
}

// Round 6
// 1117.889 us; speedup vs baseline: 1.6301x; 1.2985x over previous
//
#include <hip/hip_runtime.h>
#include <hip/hip_bf16.h>
#include <math.h>

typedef __attribute__((ext_vector_type(8))) short bf16x8;
typedef __attribute__((ext_vector_type(4))) float f32x4;

__device__ __forceinline__ float gelu_f(float x){
    float u = 0.7978845608028654f*(x + 0.044715f*x*x*x);
    float e = __expf(2.0f*u);
    float th = 1.0f - 2.0f/(e + 1.0f);
    return 0.5f*x*(1.0f + th);
}

// f32 -> bf16 bits (RNE)
__device__ __forceinline__ short f2bs(float f){
    unsigned u = __float_as_uint(f);
    u += 0x7FFF + ((u>>16)&1);
    return (short)(u>>16);
}

// ============================ Router ============================
__global__ void r_embed(const float* __restrict__ x, const float* __restrict__ ew,
                        const float* __restrict__ eb, float* __restrict__ h){
    int t = blockIdx.x*256 + threadIdx.x;           // 262144
    int d = t & 63, s = (t>>6)&127, b = t>>13;
    h[t] = x[b*16384 + s]*ew[d] + eb[d];
}

__global__ void r_qkv(const float* __restrict__ h, const float* __restrict__ w,
                      const float* __restrict__ bias, int woff, int boff,
                      float* __restrict__ qkv){
    int t = blockIdx.x*256 + threadIdx.x;           // 786432
    int j = t % 192; int sb = t/192;
    const float* hr = h + sb*64;
    float acc = bias[boff + j];
    #pragma unroll
    for(int d=0; d<64; ++d) acc += hr[d]*w[woff + d*192 + j];
    qkv[t] = acc;
}

__global__ void r_attn(const float* __restrict__ qkv, float* __restrict__ o){
    int t = blockIdx.x*256 + threadIdx.x;           // 16384
    int q = t & 127; int hd = (t>>7)&3; int b = t>>9;
    const float* base = qkv + b*128*192;
    float qv[16];
    #pragma unroll
    for(int d=0; d<16; ++d) qv[d] = base[q*192 + hd*16 + d];
    float sc[128]; float m = -1e30f;
    for(int k=0;k<128;++k){
        const float* kr = base + k*192 + 64 + hd*16;
        float acc=0.f;
        #pragma unroll
        for(int d=0;d<16;++d) acc += qv[d]*kr[d];
        acc *= 0.25f;
        sc[k]=acc; m = fmaxf(m, acc);
    }
    float sum=0.f; float ov[16];
    #pragma unroll
    for(int d=0;d<16;++d) ov[d]=0.f;
    for(int k=0;k<128;++k){
        float p = __expf(sc[k]-m); sum += p;
        const float* vr = base + k*192 + 128 + hd*16;
        #pragma unroll
        for(int d=0;d<16;++d) ov[d] += p*vr[d];
    }
    float inv = 1.0f/sum;
    float* orow = o + (b*128+q)*64 + hd*16;
    #pragma unroll
    for(int d=0;d<16;++d) orow[d] = ov[d]*inv;
}

__global__ void r_proj_res(const float* __restrict__ h, const float* __restrict__ o,
                           const float* __restrict__ w, const float* __restrict__ bias,
                           int woff, int boff, float* __restrict__ r){
    int t = blockIdx.x*256 + threadIdx.x;           // 262144
    int d = t & 63; int sb = t>>6;
    const float* orow = o + sb*64;
    float acc = bias[boff + d];
    #pragma unroll
    for(int e=0;e<64;++e) acc += orow[e]*w[woff + e*64 + d];
    r[t] = h[t] + acc;
}

__global__ void r_ln(const float* __restrict__ r, const float* __restrict__ s,
                     const float* __restrict__ bias, int off, float* __restrict__ h){
    int row = blockIdx.x*64 + threadIdx.x;          // 4096 rows
    const float* rr = r + row*64;
    float mu=0.f;
    #pragma unroll
    for(int d=0;d<64;++d) mu += rr[d];
    mu *= (1.0f/64.0f);
    float var=0.f;
    #pragma unroll
    for(int d=0;d<64;++d){ float df = rr[d]-mu; var += df*df; }
    var *= (1.0f/64.0f);
    float inv = rsqrtf(var + 1e-5f);
    float* hr = h + row*64;
    #pragma unroll
    for(int d=0;d<64;++d) hr[d] = (rr[d]-mu)*inv*s[off+d] + bias[off+d];
}

__global__ void r_ffn(const float* __restrict__ h, const float* __restrict__ w1,
                      const float* __restrict__ b1, const float* __restrict__ w2,
                      const float* __restrict__ b2,
                      int w1off, int b1off, int w2off, int b2off,
                      float* __restrict__ r){
    __shared__ float hrow[64];
    __shared__ float uval[256];
    int row = blockIdx.x;                           // 4096
    int tid = threadIdx.x;                          // 256
    if(tid < 64) hrow[tid] = h[row*64 + tid];
    __syncthreads();
    {
        float acc = b1[b1off + tid];
        #pragma unroll
        for(int d=0; d<64; ++d) acc += hrow[d]*w1[w1off + d*256 + tid];
        uval[tid] = fmaxf(acc, 0.0f);
    }
    __syncthreads();
    if(tid < 64){
        float acc = b2[b2off + tid];
        for(int j=0;j<256;++j) acc += uval[j]*w2[w2off + j*64 + tid];
        r[row*64 + tid] = hrow[tid] + acc;
    }
}

__global__ void r_head(const float* __restrict__ h, const float* __restrict__ fcw,
                       const float* __restrict__ fcb, int* __restrict__ idx){
    __shared__ float feats[64];
    __shared__ float lg[8];
    int b = blockIdx.x; int d = threadIdx.x;        // 64 threads
    float acc=0.f;
    for(int s2=0;s2<128;++s2) acc += h[(b*128+s2)*64 + d];
    feats[d] = acc*(1.0f/128.0f);
    __syncthreads();
    if(d<8){
        float a = fcb[d];
        for(int e=0;e<64;++e) a += feats[e]*fcw[e*8+d];
        lg[d]=a;
    }
    __syncthreads();
    if(d==0){
        int best=0; float bv=lg[0];
        for(int e=1;e<8;++e) if(lg[e]>bv){bv=lg[e];best=e;}
        idx[b]=best;
    }
}

// ============================ FNO (batch-chunked) ============================
__global__ void f_lift(const float* __restrict__ x, const float* __restrict__ lw,
                       const float* __restrict__ lb, const int* __restrict__ idx,
                       int b0, float* __restrict__ v){
    int t = blockIdx.x*256 + threadIdx.x;           // nb*524288
    int w = t & 127; int h2 = (t>>7)&127; int d = (t>>14)&31; int bl = t>>19;
    int b = b0 + bl;
    int e = idx[b];
    v[t] = x[b*16384 + h2*128 + w]*lw[e*32+d] + lb[e*32+d];
}

// fused forward DFT: w-DFT (radix-4 + ky recurrence) -> LDS -> h-DFT.
// Block handles 2 bi = (bl*32+i). Output G[bi][kxi][ky] complex.
__global__ __launch_bounds__(256) void f_fwd(const float* __restrict__ v,
                                             float* __restrict__ G){
    __shared__ float cT[128], sT[128];
    __shared__ float X[2*16*260 + 8];               // [bil][ky][h*2], ky-stride 260
    int tid = threadIdx.x;                          // 256
    if(tid<128){ float sv,cv; __sincosf(6.283185307179586f*tid/128.0f,&sv,&cv); cT[tid]=cv; sT[tid]=sv; }
    __syncthreads();
    int bi0 = blockIdx.x*2;
    {   // ---- phase 1: DFT along w for 16 ky modes ----
        int bil = tid>>7, h = tid&127;
        const float* row = v + ((bi0+bil)*128 + h)*128;
        float Xr[16], Xi[16];
        #pragma unroll
        for(int k=0;k<16;++k){ Xr[k]=0.f; Xi[k]=0.f; }
        #pragma unroll
        for(int j=0;j<8;++j){
            float4 a = *(const float4*)(row + 4*j);
            float4 bq= *(const float4*)(row + 4*j + 32);
            float4 c = *(const float4*)(row + 4*j + 64);
            float4 dq= *(const float4*)(row + 4*j + 96);
            #pragma unroll
            for(int r=0;r<4;++r){
                int g = 4*j + r;
                float va = (r==0)?a.x:(r==1)?a.y:(r==2)?a.z:a.w;
                float vb = (r==0)?bq.x:(r==1)?bq.y:(r==2)?bq.z:bq.w;
                float vc = (r==0)?c.x:(r==1)?c.y:(r==2)?c.z:c.w;
                float vd = (r==0)?dq.x:(r==1)?dq.y:(r==2)?dq.z:dq.w;
                float s1=va+vc, s2=vb+vd, d1=va-vc, d2=vb-vd;
                float rsum=s1+s2, rdif=s1-s2;
                float pc=cT[g], ps=-sT[g];          // p = e^{-i g θ}
                float cr=1.f, ci=0.f;
                #pragma unroll
                for(int ky=0;ky<16;++ky){
                    int mm = ky&3;
                    if(mm==0){ Xr[ky]+=cr*rsum; Xi[ky]+=ci*rsum; }
                    else if(mm==1){ Xr[ky]+=cr*d1+ci*d2; Xi[ky]+=ci*d1-cr*d2; }
                    else if(mm==2){ Xr[ky]+=cr*rdif; Xi[ky]+=ci*rdif; }
                    else { Xr[ky]+=cr*d1-ci*d2; Xi[ky]+=ci*d1+cr*d2; }
                    float tt=cr*pc-ci*ps; ci=cr*ps+ci*pc; cr=tt;
                }
            }
        }
        float* Xb = X + bil*4160;
        #pragma unroll
        for(int ky=0;ky<16;++ky){
            Xb[ky*260 + h*2]   = Xr[ky];
            Xb[ky*260 + h*2+1] = Xi[ky];
        }
    }
    __syncthreads();
    {   // ---- phase 2: DFT along h at kx in {0..15,112..127} ----
        int ky = tid&15, kg = (tid>>4)&7, bil = tid>>7;
        int bi = bi0 + bil;
        const float* Xb = X + bil*4160 + ky*260;
        int kxs[4] = {kg, kg+8, kg+112, kg+120};
        float qc[4], qs[4];
        #pragma unroll
        for(int m2=0;m2<4;++m2){ qc[m2]=cT[kxs[m2]&127]; qs[m2]=-sT[kxs[m2]&127]; }
        float cr[4]={1.f,1.f,1.f,1.f}, ci[4]={0.f,0.f,0.f,0.f};
        float Gr[4]={0.f,0.f,0.f,0.f}, Gi[4]={0.f,0.f,0.f,0.f};
        for(int h=0;h<128;++h){
            float Xr=Xb[h*2], Xi2=Xb[h*2+1];
            #pragma unroll
            for(int m2=0;m2<4;++m2){
                Gr[m2] += Xr*cr[m2] - Xi2*ci[m2];
                Gi[m2] += Xr*ci[m2] + Xi2*cr[m2];
                float t=cr[m2]*qc[m2]-ci[m2]*qs[m2]; ci[m2]=cr[m2]*qs[m2]+ci[m2]*qc[m2]; cr[m2]=t;
            }
        }
        #pragma unroll
        for(int m2=0;m2<4;++m2){
            int kxi = kg + 8*m2;
            G[((bi*32+kxi)*16+ky)*2]   = Gr[m2];
            G[((bi*32+kxi)*16+ky)*2+1] = Gi[m2];
        }
    }
}

__global__ void f_specmul(const float* __restrict__ G, const float* __restrict__ wr,
                          const float* __restrict__ wi, const int* __restrict__ idx,
                          int l, int b0, float* __restrict__ Go){
    int t = blockIdx.x*256 + threadIdx.x;           // nb*16384
    int ky = t & 15; int kxi = (t>>4)&31; int o = (t>>9)&31; int bl = t>>14;
    int e = __builtin_amdgcn_readfirstlane(idx[b0 + bl]);
    int side = (kxi>=16) ? 1 : 0; int xm = kxi & 15;
    int wbase = ((((e*4+l)*2+side)*32)*32 + o)*256 + xm*16 + ky;
    const float* gp = G + ((bl*1024 + kxi)*16 + ky)*2;
    float orr=0.f, oii=0.f;
    #pragma unroll 8
    for(int i=0;i<32;++i){
        float gr = gp[i*1024], gi = gp[i*1024+1];
        float wrv = wr[wbase + i*8192];
        float wiv = wi[wbase + i*8192];
        orr += gr*wrv - gi*wiv;
        oii += gr*wiv + gi*wrv;
    }
    Go[t*2]=orr; Go[t*2+1]=oii;
}

// inverse DFT along h. Block per bo=(bl,o), thread=h. Go block-uniform -> s_load.
__global__ __launch_bounds__(128) void f_idft_h(const float* __restrict__ Go,
                                                float* __restrict__ T){
    __shared__ float cT[128], sT[128];
    int tid = threadIdx.x;                          // 128
    { float sv,cv; __sincosf(6.283185307179586f*tid/128.0f,&sv,&cv); cT[tid]=cv; sT[tid]=sv; }
    __syncthreads();
    int bo = blockIdx.x;
    const float* g = Go + bo*1024;                  // [kxi][ky] cplx
    int h = tid;
    float Mc = cT[h], Ms = sT[h];                   // e^{+i h θ}
    float Tr[16], Ti[16];
    #pragma unroll
    for(int k=0;k<16;++k){ Tr[k]=0.f; Ti[k]=0.f; }
    {   float cr=1.f, ci=0.f;
        for(int kxi=0;kxi<16;++kxi){
            #pragma unroll
            for(int ky=0;ky<16;++ky){
                float gr=g[(kxi*16+ky)*2], gi=g[(kxi*16+ky)*2+1];
                Tr[ky] += gr*cr - gi*ci;
                Ti[ky] += gr*ci + gi*cr;
            }
            float t=cr*Mc-ci*Ms; ci=cr*Ms+ci*Mc; cr=t;
        }
    }
    {   float cr=1.f, ci=0.f;
        for(int m=1;m<=16;++m){
            float t=cr*Mc+ci*Ms; ci=ci*Mc-cr*Ms; cr=t;   // *= conj
            int kxi = 32 - m;
            #pragma unroll
            for(int ky=0;ky<16;++ky){
                float gr=g[(kxi*16+ky)*2], gi=g[(kxi*16+ky)*2+1];
                Tr[ky] += gr*cr - gi*ci;
                Ti[ky] += gr*ci + gi*cr;
            }
        }
    }
    float* out = T + (bo*128 + h)*32;
    #pragma unroll
    for(int k=0;k<8;++k){
        *(float4*)(out + 4*k) = make_float4(Tr[2*k], Ti[2*k], Tr[2*k+1], Ti[2*k+1]);
    }
}

// C2R inverse along w (16 modes) + skip matmul + bias + gelu. IN-PLACE on v.
__global__ __launch_bounds__(128) void f_inv_w_skip(const float* __restrict__ T,
                             float* __restrict__ v,
                             const float* __restrict__ skw, const float* __restrict__ skb,
                             const int* __restrict__ idx, int l, int act, int b0){
    __shared__ float cT[128], sT[128];
    int tid = threadIdx.x;                          // 128
    { float sv,cv; __sincosf(6.283185307179586f*tid/128.0f,&sv,&cv); cT[tid]=cv; sT[tid]=sv; }
    __syncthreads();
    int bl = blockIdx.x >> 7; int h2 = blockIdx.x & 127;
    int e = __builtin_amdgcn_readfirstlane(idx[b0 + bl]);
    int w = tid;
    float vv[32];
    #pragma unroll
    for(int i=0;i<32;++i) vv[i] = v[((bl*32+i)*128+h2)*128 + w];
    const float* swp = skw + (e*4+l)*1024;
    const float* sbp = skb + (e*4+l)*32;
    float acc[32];
    #pragma unroll
    for(int o=0;o<32;++o) acc[o] = sbp[o];
    for(int i=0;i<32;++i){
        float vi = vv[i];
        const float* wrow = swp + i*32;
        #pragma unroll
        for(int o=0;o<32;++o) acc[o] += vi*wrow[o];
    }
    float C[16], S[16];
    {
        float bc=cT[w], bs=sT[w];
        float cr=bc, ci=bs;
        C[0]=1.f; S[0]=0.f;
        #pragma unroll
        for(int ky=1;ky<16;++ky){
            C[ky]=2.f*cr; S[ky]=2.f*ci;
            float t=cr*bc-ci*bs; ci=cr*bs+ci*bc; cr=t;
        }
    }
    for(int o=0;o<32;++o){
        const float* Tb = T + ((bl*32+o)*128 + h2)*32;
        float spec = Tb[0];
        #pragma unroll
        for(int ky=1;ky<16;++ky) spec += Tb[2*ky]*C[ky] - Tb[2*ky+1]*S[ky];
        float val = spec*(1.0f/16384.0f) + acc[o];
        if(act) val = gelu_f(val);
        v[((bl*32+o)*128+h2)*128 + w] = val;
    }
}

// final projection via MFMA bf16: per M-tile of 16 pixels,
// p1 GEMM (K=32, N=128 as 8 og tiles) -> gelu -> dot w2 -> out.
__global__ __launch_bounds__(256) void f_proj(const float* __restrict__ vin,
                       const float* __restrict__ p1w, const float* __restrict__ p1b,
                       const float* __restrict__ p2w, const float* __restrict__ p2b,
                       const int* __restrict__ idx, int b0, float* __restrict__ out){
    int tid = threadIdx.x;
    int wv  = tid>>6, lane = tid&63;
    int blk = blockIdx.x;                           // nb*32 blocks, 32 per batch
    int bl  = blk>>5; int part = blk&31;
    int b   = b0 + bl;
    int e   = __builtin_amdgcn_readfirstlane(idx[b]);
    int m   = lane&15, quad = lane>>4;
    // B-fragments (W1 tiles) + per-lane b1/w2 scalars; loaded once per wave.
    const float* w1 = p1w + e*4096;                 // [k=32][o=128]
    bf16x8 bfr[8]; float b1v[8], w2v[8];
    #pragma unroll
    for(int og=0; og<8; ++og){
        int o = og*16 + m;
        #pragma unroll
        for(int j=0;j<8;++j){
            int k = quad*8 + j;
            bfr[og][j] = f2bs(w1[k*128 + o]);
        }
        b1v[og] = p1b[e*128+o];
        w2v[og] = p2w[e*128+o];
    }
    float p2bv = p2b[e];
    const float* vbase = vin + (size_t)bl*524288;
    for(int t=0;t<8;++t){
        int tile = part*32 + wv*8 + t;              // 1024 tiles per batch
        int pix0 = tile*16;
        bf16x8 af;
        #pragma unroll
        for(int j=0;j<8;++j){
            int k = quad*8 + j;
            af[j] = f2bs(vbase[k*16384 + pix0 + m]);
        }
        float acc0=0.f, acc1=0.f, acc2=0.f, acc3=0.f;
        #pragma unroll
        for(int og=0;og<8;++og){
            f32x4 d = {0.f,0.f,0.f,0.f};
            d = __builtin_amdgcn_mfma_f32_16x16x32_bf16(af, bfr[og], d, 0,0,0);
            acc0 += w2v[og]*gelu_f(d[0]+b1v[og]);
            acc1 += w2v[og]*gelu_f(d[1]+b1v[og]);
            acc2 += w2v[og]*gelu_f(d[2]+b1v[og]);
            acc3 += w2v[og]*gelu_f(d[3]+b1v[og]);
        }
        #pragma unroll
        for(int s=1;s<16;s<<=1){
            acc0 += __shfl_xor(acc0, s, 64);
            acc1 += __shfl_xor(acc1, s, 64);
            acc2 += __shfl_xor(acc2, s, 64);
            acc3 += __shfl_xor(acc3, s, 64);
        }
        if(m==0){
            int pix = pix0 + quad*4;                // 4 consecutive pixels
            *(float4*)(out + (size_t)b*16384 + pix) =
                make_float4(acc0+p2bv, acc1+p2bv, acc2+p2bv, acc3+p2bv);
        }
    }
}

// ============================ launch ============================
extern "C" void kernel_launch(void* const* d_in, const int* in_sizes, int n_in,
                              void* d_out, int out_size, void* d_ws, size_t ws_size,
                              hipStream_t stream){
    const float* x      = (const float*)d_in[0];
    const float* enc_w  = (const float*)d_in[1];
    const float* enc_b  = (const float*)d_in[2];
    const float* qkv_w  = (const float*)d_in[3];
    const float* qkv_b  = (const float*)d_in[4];
    const float* ao_w   = (const float*)d_in[5];
    const float* ao_b   = (const float*)d_in[6];
    const float* ln1_s  = (const float*)d_in[7];
    const float* ln1_b  = (const float*)d_in[8];
    const float* ff1_w  = (const float*)d_in[9];
    const float* ff1_b  = (const float*)d_in[10];
    const float* ff2_w  = (const float*)d_in[11];
    const float* ff2_b  = (const float*)d_in[12];
    const float* ln2_s  = (const float*)d_in[13];
    const float* ln2_b  = (const float*)d_in[14];
    const float* fc_w   = (const float*)d_in[15];
    const float* fc_b   = (const float*)d_in[16];
    const float* lift_w = (const float*)d_in[17];
    const float* lift_b = (const float*)d_in[18];
    const float* spec_wr= (const float*)d_in[19];
    const float* spec_wi= (const float*)d_in[20];
    const float* skip_w = (const float*)d_in[21];
    const float* skip_b = (const float*)d_in[22];
    const float* p1_w   = (const float*)d_in[23];
    const float* p1_b   = (const float*)d_in[24];
    const float* p2_w   = (const float*)d_in[25];
    const float* p2_b   = (const float*)d_in[26];

    // workspace: header 64 floats; FNO chunk of nb batches = nb*851968 floats
    // (v 524288 + spare 131072 + G 32768 + Go 32768 + T 131072). Router
    // scratch (1,572,864 fl) aliases the FNO region (router completes first).
    int*   idx   = (int*)d_ws + 8;
    float* base  = (float*)d_ws + 64;

    size_t avail_fl = (ws_size/4 > 64) ? (ws_size/4 - 64) : 0;
    int nb = 1;
    for(int c = 32; c >= 1; c >>= 1){
        if((size_t)c*851968 <= avail_fl){ nb = c; break; }
    }

    float* hbuf  = base;                         // 262144
    float* qkvb  = hbuf + 262144;                // 786432
    float* obuf  = qkvb + 786432;                // 262144
    float* rbuf  = obuf + 262144;                // 262144

    // ---- router ----
    r_embed<<<1024,256,0,stream>>>(x, enc_w, enc_b, hbuf);
    for(int l=0;l<2;++l){
        r_qkv<<<3072,256,0,stream>>>(hbuf, qkv_w, qkv_b, l*64*192, l*192, qkvb);
        r_attn<<<64,256,0,stream>>>(qkvb, obuf);
        r_proj_res<<<1024,256,0,stream>>>(hbuf, obuf, ao_w, ao_b, l*64*64, l*64, rbuf);
        r_ln<<<64,64,0,stream>>>(rbuf, ln1_s, ln1_b, l*64, hbuf);
        r_ffn<<<4096,256,0,stream>>>(hbuf, ff1_w, ff1_b, ff2_w, ff2_b,
                                     l*64*256, l*256, l*256*64, l*64, rbuf);
        r_ln<<<64,64,0,stream>>>(rbuf, ln2_s, ln2_b, l*64, hbuf);
    }
    r_head<<<32,64,0,stream>>>(hbuf, fc_w, fc_b, idx);

    // ---- FNO, batch-chunked ----
    for(int b0 = 0; b0 < 32; b0 += nb){
        float* vC = base;                        // nb*524288
        float* G  = vC + (size_t)nb*655360;      // nb*32768
        float* Go = G  + (size_t)nb*32768;       // nb*32768
        float* T  = Go + (size_t)nb*32768;       // nb*131072

        f_lift<<<nb*2048,256,0,stream>>>(x, lift_w, lift_b, idx, b0, vC);
        for(int l=0;l<4;++l){
            f_fwd    <<<nb*16, 256,0,stream>>>(vC, G);
            f_specmul<<<nb*64, 256,0,stream>>>(G, spec_wr, spec_wi, idx, l, b0, Go);
            f_idft_h <<<nb*32, 128,0,stream>>>(Go, T);
            f_inv_w_skip<<<nb*128,128,0,stream>>>(T, vC, skip_w, skip_b, idx,
                                                  l, (l<3)?1:0, b0);
        }
        f_proj<<<nb*32,256,0,stream>>>(vC, p1_w, p1_b, p2_w, p2_b, idx, b0,
                                       (float*)d_out);
    }
}